// Round 2
// baseline (228.494 us; speedup 1.0000x reference)
//
#include <hip/hip_runtime.h>
#include <math.h>

#define V 32768
#define D 15
#define DM 1024
#define B 8
#define T 1024
#define NNODES (V - 1)  // 32767
#define R 8             // rows per wave

// Kernel 1: sig[v*B + b] = sigmoid(dot(W[v], x[b]) + bias[v]) for all internal nodes v.
// Block = 256 threads (4 waves), R=8 rows per wave -> 32 rows/block.
// K dimension split across the 64 lanes (4 float4 per lane); W loads are 1 KB
// contiguous per instruction. x staged once per block in LDS; each k-iter reads
// the 8 x-float4 once and reuses them across 8 W rows (4x less LDS traffic than R=2).
// Reduction: multi-value butterfly — folds 64 lane-partial accumulators into one
// register in 63 shuffles total; lane L ends holding the full sum for acc index L
// (r = L>>3, b = L&7), so the store is 64 contiguous floats.
__global__ __launch_bounds__(256, 3) void hsm_logits_kernel(
    const float* __restrict__ x,     // [B][DM]
    const float* __restrict__ W,     // [NNODES][DM]
    const float* __restrict__ bias,  // [NNODES]
    float* __restrict__ sig)         // [NNODES][B]
{
    __shared__ float4 xs[B * DM / 4];  // 2048 float4 = 32 KB, xs[b*256 + u]

    const float4* x4 = (const float4*)x;
    #pragma unroll
    for (int i = threadIdx.x; i < B * DM / 4; i += 256) xs[i] = x4[i];
    __syncthreads();

    const int wave = threadIdx.x >> 6;
    const int lane = threadIdx.x & 63;
    const int row0 = (blockIdx.x * 4 + wave) * R;
    if (row0 >= NNODES) return;

    const float4* Wb = (const float4*)W;

    float acc[R * B];  // acc[r*8+b]
    #pragma unroll
    for (int i = 0; i < R * B; i++) acc[i] = 0.f;

    // 256 float4 per row; lane covers u = j*64 + lane for j=0..3.
    #pragma unroll
    for (int j = 0; j < 4; j++) {
        const int u = j * 64 + lane;
        float4 xv[B];
        #pragma unroll
        for (int b = 0; b < B; b++) xv[b] = xs[b * 256 + u];
        #pragma unroll
        for (int r = 0; r < R; r++) {
            int row = row0 + r;
            if (row > NNODES - 1) row = NNODES - 1;  // clamp; store is guarded below
            const float4 wv = Wb[(size_t)row * 256 + u];
            #pragma unroll
            for (int b = 0; b < B; b++) {
                acc[r * 8 + b] += wv.x * xv[b].x + wv.y * xv[b].y +
                                  wv.z * xv[b].z + wv.w * xv[b].w;
            }
        }
    }

    // Multi-value butterfly fold: at level m, accs (2i, 2i+1) fold into slot i;
    // lanes with bit m clear keep the even lineage, bit m set keep the odd.
    // Levels m=1..32 ascending => final acc index == lane index.
    #pragma unroll
    for (int m = 1, n = R * B; m <= 32; m <<= 1, n >>= 1) {
        #pragma unroll
        for (int i = 0; i < 64; i++) {  // bounded by compile-time n below
            if (i < n / 2) {
                const float lo = acc[2 * i];
                const float hi = acc[2 * i + 1];
                const float send = (lane & m) ? lo : hi;
                const float keep = (lane & m) ? hi : lo;
                const float recv = __shfl_xor(send, m, 64);
                acc[i] = keep + recv;
            }
        }
    }

    const int r = lane >> 3;
    const int b = lane & 7;
    const int row = row0 + r;
    if (row < NNODES) {
        const float z = acc[0] + bias[row];
        sig[(size_t)row * B + b] = 1.f / (1.f + expf(-z));
    }
}

// Kernel 2: out[b*T + t] = prod_{d} sig[paths[ids[b][t]][d] * B + b]
__global__ __launch_bounds__(256) void hsm_prod_kernel(
    const int* __restrict__ ids,    // [B][T]
    const int* __restrict__ paths,  // [V][D]
    const float* __restrict__ sig,  // [NNODES][B]
    float* __restrict__ out)        // [B][T]
{
    const int i = blockIdx.x * blockDim.x + threadIdx.x;
    if (i >= B * T) return;
    const int b = i / T;
    const int id = ids[i];
    const int* p = paths + (size_t)id * D;
    float prod = 1.f;
    #pragma unroll
    for (int d = 0; d < D; d++) {
        prod *= sig[(size_t)p[d] * B + b];
    }
    out[i] = prod;
}

extern "C" void kernel_launch(void* const* d_in, const int* in_sizes, int n_in,
                              void* d_out, int out_size, void* d_ws, size_t ws_size,
                              hipStream_t stream) {
    const float* x     = (const float*)d_in[0];  // [B, DM]
    const int*   ids   = (const int*)d_in[1];    // [B, T]
    const int*   paths = (const int*)d_in[2];    // [V, D]
    const float* W     = (const float*)d_in[3];  // [NNODES, DM]
    const float* bias  = (const float*)d_in[4];  // [NNODES]
    float* out = (float*)d_out;                  // [B, T]
    float* sig = (float*)d_ws;                   // [NNODES, B] = 1 MB scratch

    const int rows_per_block = 4 * R;  // 4 waves x 8 rows = 32
    const int grid1 = (NNODES + rows_per_block - 1) / rows_per_block;  // 1024
    hsm_logits_kernel<<<grid1, 256, 0, stream>>>(x, W, bias, sig);

    const int grid2 = (B * T + 255) / 256;  // 32
    hsm_prod_kernel<<<grid2, 256, 0, stream>>>(ids, paths, sig, out);
}